// Round 3
// baseline (74.840 us; speedup 1.0000x reference)
//
#include <hip/hip_runtime.h>
#include <math.h>

// Problem constants (fixed by setup_inputs)
#define BATCH   2
#define NS      8192
#define NT      2048
#define KNN     64
#define CH      64
#define NSH     16
#define SC      192           // NUM_SHELLS * CH
#define YROW    3072          // 16 * 192
#define FSTR    72            // bf16 stride for feats LDS rows
#define KSTR    72            // bf16 stride for kern LDS rows

// round-to-nearest-even float -> bf16 bits
__device__ inline unsigned short f2bf(float x) {
    unsigned u = __float_as_uint(x);
    unsigned r = (u + 0x7fffu + ((u >> 16) & 1u)) >> 16;
    return (unsigned short)r;
}
__device__ inline float blo(unsigned v) { return __uint_as_float(v << 16); }
__device__ inline float bhi(unsigned v) { return __uint_as_float(v & 0xffff0000u); }

// ---------------------------------------------------------------------------
// Kernel 1: SH-Gaussian kernels + neighbor gather + contraction.
// One 64-thread wave per (b,n) point. bf16 LDS operands; y stored bf16.
// Thread owns 2 ys x 3 s x 8 c. LDS reads: 48 kern b128 + 64 feats b128.
// ---------------------------------------------------------------------------
__global__ __launch_bounds__(64, 2) void sh_conv_kernel(
    const float* __restrict__ src,      // (B,NS,CH)
    const float* __restrict__ patches,  // (B,NT,K,3)
    const float* __restrict__ pdist,    // (B,NT,K)
    const int*   __restrict__ pidx,     // (B,NT,K)
    unsigned short* __restrict__ y)     // (B,NT,16,192) bf16
{
    __shared__ unsigned short kern[48 * KSTR];   // [row=ys*3+s][k] 6912 B
    __shared__ unsigned short feats[KNN * FSTR]; // [k][c] 9216 B

    const int pt = blockIdx.x;           // b*NT + n
    const int b  = pt >> 11;             // NT = 2048
    const int l  = threadIdx.x;          // 0..63
    const int g  = l >> 4;               // 0..3
    const int m  = l & 15;               // 0..15

    // ---- Phase A1: gather neighbor features -> bf16 LDS ----
    {
        const int* idxp = pidx + pt * KNN;
        #pragma unroll 4
        for (int p = 0; p < 16; ++p) {
            const int k  = 4 * p + g;
            const int id = idxp[k];
            const float4 v = *(const float4*)(src + ((size_t)(b * NS + id)) * CH + m * 4);
            unsigned wa = (unsigned)f2bf(v.x) | ((unsigned)f2bf(v.y) << 16);
            unsigned wb = (unsigned)f2bf(v.z) | ((unsigned)f2bf(v.w) << 16);
            *(uint2*)&feats[k * FSTR + m * 4] = make_uint2(wa, wb);
        }
    }

    // ---- Phase A2: kern[(ys*3+s)][k] = bf16( sh[ys]*w[s]/64 ), lane = k ----
    {
        const int k = l;
        const float* pv = patches + ((size_t)pt * KNN + k) * 3;
        const float px = pv[0], py = pv[1], pz = pv[2];
        const float d  = pdist[pt * KNN + k];
        const float inv = 1.0f / (d + 1e-8f);
        const float x = px * inv, yy = py * inv, z = pz * inv;
        const float x2 = x * x, y2 = yy * yy, z2 = z * z;

        float sh[16];
        sh[0]  = 0.28209479177387814f;
        sh[1]  = 0.4886025119029199f * yy;
        sh[2]  = 0.4886025119029199f * z;
        sh[3]  = 0.4886025119029199f * x;
        sh[4]  = 1.0925484305920792f * x * yy;
        sh[5]  = 1.0925484305920792f * yy * z;
        sh[6]  = 0.31539156525252005f * (3.0f * z2 - 1.0f);
        sh[7]  = 1.0925484305920792f * x * z;
        sh[8]  = 0.5462742152960396f * (x2 - y2);
        sh[9]  = 0.5900435899266435f * yy * (3.0f * x2 - y2);
        sh[10] = 2.890611442640554f  * x * yy * z;
        sh[11] = 0.4570457994644658f * yy * (5.0f * z2 - 1.0f);
        sh[12] = 0.3731763325901154f * z * (5.0f * z2 - 3.0f);
        sh[13] = 0.4570457994644658f * x * (5.0f * z2 - 1.0f);
        sh[14] = 1.445305721320277f  * z * (x2 - y2);
        sh[15] = 0.5900435899266435f * x * (x2 - 3.0f * y2);

        const float GS = 6.23832462504f;            // ln2 * 9
        float w0 = expf(-GS * d * d);
        const float dm1 = d - 0.5f;
        float w1 = expf(-GS * dm1 * dm1);
        const float dm2 = d - 1.0f;
        float w2 = expf(-GS * dm2 * dm2);
        const float wn = ((d <= 1.0f) ? 1.0f : 0.0f) * (1.0f / 64.0f)
                         / (w0 + w1 + w2 + 1e-8f);  // fold 1/K
        w0 *= wn; w1 *= wn; w2 *= wn;

        #pragma unroll
        for (int ys = 0; ys < 16; ++ys) {
            const float s = sh[ys];
            kern[(ys * 3 + 0) * KSTR + k] = f2bf(s * w0);
            kern[(ys * 3 + 1) * KSTR + k] = f2bf(s * w1);
            kern[(ys * 3 + 2) * KSTR + k] = f2bf(s * w2);
        }
    }
    __syncthreads();

    // ---- Phase B: thread (yg,cg) owns ys in {2yg,2yg+1}, cols 8cg..8cg+7 ----
    const int yg = l >> 3;               // 0..7
    const int cg = l & 7;                // 0..7
    float acc[6][8];
    #pragma unroll
    for (int r = 0; r < 6; ++r)
        #pragma unroll
        for (int c = 0; c < 8; ++c) acc[r][c] = 0.f;

    for (int q = 0; q < 8; ++q) {        // k-octet
        uint4 kr[6];
        #pragma unroll
        for (int r = 0; r < 6; ++r)
            kr[r] = *(const uint4*)&kern[(yg * 6 + r) * KSTR + q * 8];
        #pragma unroll
        for (int j = 0; j < 8; ++j) {
            const uint4 f = *(const uint4*)&feats[(q * 8 + j) * FSTR + cg * 8];
            float fv[8];
            fv[0] = blo(f.x); fv[1] = bhi(f.x);
            fv[2] = blo(f.y); fv[3] = bhi(f.y);
            fv[4] = blo(f.z); fv[5] = bhi(f.z);
            fv[6] = blo(f.w); fv[7] = bhi(f.w);
            #pragma unroll
            for (int r = 0; r < 6; ++r) {
                const unsigned kw = ((const unsigned*)&kr[r])[j >> 1];
                const float kv = (j & 1) ? bhi(kw) : blo(kw);
                #pragma unroll
                for (int c = 0; c < 8; ++c) acc[r][c] += kv * fv[c];
            }
        }
    }

    // ---- Store: y[pt][ys][s*64 + 8cg .. +7] bf16 ----
    unsigned short* yb = y + (size_t)pt * YROW + cg * 8;
    #pragma unroll
    for (int ys2 = 0; ys2 < 2; ++ys2) {
        #pragma unroll
        for (int s = 0; s < 3; ++s) {
            const float* a = acc[ys2 * 3 + s];
            uint4 o;
            o.x = (unsigned)f2bf(a[0]) | ((unsigned)f2bf(a[1]) << 16);
            o.y = (unsigned)f2bf(a[2]) | ((unsigned)f2bf(a[3]) << 16);
            o.z = (unsigned)f2bf(a[4]) | ((unsigned)f2bf(a[5]) << 16);
            o.w = (unsigned)f2bf(a[6]) | ((unsigned)f2bf(a[7]) << 16);
            *(uint4*)(yb + (2 * yg + ys2) * SC + s * CH) = o;
        }
    }
}

// ---------------------------------------------------------------------------
// Kernel 2: inverse-square-distance propagation + per-degree norms.
// 192 threads = 8 points x 24 col-groups; loads batched 12 uint4 at a time
// for deep ILP (latency-limited kernel). VGPR cap 128 via launch_bounds.
// ---------------------------------------------------------------------------
__global__ __launch_bounds__(192, 4) void prop_norm_kernel(
    const unsigned short* __restrict__ y, // (B,NT,16,192) bf16
    const int*   __restrict__ prop_idx,   // (B,NS,3)
    const float* __restrict__ prop_dist,  // (B,NS,3)
    float* __restrict__ out)              // (B,NS,768)
{
    const int t  = threadIdx.x;
    const int lp = t / 24;                // local point 0..7
    const int u  = t % 24;                // col-group: cols 8u..8u+7
    const int pt = blockIdx.x * 8 + lp;   // b*NS + ns
    const int b  = pt >> 13;              // NS = 8192

    const int   i0 = prop_idx[pt * 3 + 0];
    const int   i1 = prop_idx[pt * 3 + 1];
    const int   i2 = prop_idx[pt * 3 + 2];
    const float d0 = prop_dist[pt * 3 + 0];
    const float d1 = prop_dist[pt * 3 + 1];
    const float d2 = prop_dist[pt * 3 + 2];

    float w0 = 1.0f / (d0 * d0 + 1e-8f);
    float w1 = 1.0f / (d1 * d1 + 1e-8f);
    float w2 = 1.0f / (d2 * d2 + 1e-8f);
    const float wi = 1.0f / (w0 + w1 + w2);
    w0 *= wi; w1 *= wi; w2 *= wi;

    const uint4* p0 = (const uint4*)(y + ((size_t)(b * NT + i0)) * YROW) + u;
    const uint4* p1 = (const uint4*)(y + ((size_t)(b * NT + i1)) * YROW) + u;
    const uint4* p2 = (const uint4*)(y + ((size_t)(b * NT + i2)) * YROW) + u;
    // per-ys stride in uint4 units: 192 bf16 = 24 uint4

    float nsum[4][8];
    #pragma unroll
    for (int lq = 0; lq < 4; ++lq)
        #pragma unroll
        for (int j = 0; j < 8; ++j) nsum[lq][j] = 0.f;

    #pragma unroll
    for (int gq = 0; gq < 4; ++gq) {      // 4 batches of 4 ys
        uint4 A[4], Bv[4], Cv[4];
        #pragma unroll
        for (int j = 0; j < 4; ++j) {
            A[j]  = p0[(gq * 4 + j) * 24];
            Bv[j] = p1[(gq * 4 + j) * 24];
            Cv[j] = p2[(gq * 4 + j) * 24];
        }
        #pragma unroll
        for (int j = 0; j < 4; ++j) {
            const int ys = gq * 4 + j;
            const int lidx = (ys == 0) ? 0 : (ys < 4) ? 1 : (ys < 9) ? 2 : 3;
            const unsigned aw[4] = {A[j].x,  A[j].y,  A[j].z,  A[j].w};
            const unsigned bw[4] = {Bv[j].x, Bv[j].y, Bv[j].z, Bv[j].w};
            const unsigned cw[4] = {Cv[j].x, Cv[j].y, Cv[j].z, Cv[j].w};
            #pragma unroll
            for (int q = 0; q < 4; ++q) {
                const float vlo = w0 * blo(aw[q]) + w1 * blo(bw[q]) + w2 * blo(cw[q]);
                const float vhi = w0 * bhi(aw[q]) + w1 * bhi(bw[q]) + w2 * bhi(cw[q]);
                nsum[lidx][2 * q]     += vlo * vlo;
                nsum[lidx][2 * q + 1] += vhi * vhi;
            }
        }
    }

    float* ob = out + (size_t)pt * (4 * SC) + u * 8;
    #pragma unroll
    for (int lq = 0; lq < 4; ++lq) {
        float4 o0, o1;
        o0.x = sqrtf(fmaxf(nsum[lq][0], 1e-8f));
        o0.y = sqrtf(fmaxf(nsum[lq][1], 1e-8f));
        o0.z = sqrtf(fmaxf(nsum[lq][2], 1e-8f));
        o0.w = sqrtf(fmaxf(nsum[lq][3], 1e-8f));
        o1.x = sqrtf(fmaxf(nsum[lq][4], 1e-8f));
        o1.y = sqrtf(fmaxf(nsum[lq][5], 1e-8f));
        o1.z = sqrtf(fmaxf(nsum[lq][6], 1e-8f));
        o1.w = sqrtf(fmaxf(nsum[lq][7], 1e-8f));
        *(float4*)(ob + lq * SC)     = o0;
        *(float4*)(ob + lq * SC + 4) = o1;
    }
}

// ---------------------------------------------------------------------------
extern "C" void kernel_launch(void* const* d_in, const int* in_sizes, int n_in,
                              void* d_out, int out_size, void* d_ws, size_t ws_size,
                              hipStream_t stream) {
    const float* src       = (const float*)d_in[0];  // source_feats (B,NS,CH)
    const float* patches   = (const float*)d_in[1];  // (B,NT,K,3)
    const float* pdist     = (const float*)d_in[2];  // (B,NT,K)
    const int*   pidx      = (const int*)d_in[3];    // (B,NT,K)
    const int*   prop_idx  = (const int*)d_in[4];    // (B,NS,PP)
    const float* prop_dist = (const float*)d_in[5];  // (B,NS,PP)
    float*       out       = (float*)d_out;          // (B,NS,768)
    unsigned short* y_ws   = (unsigned short*)d_ws;  // (B,NT,16,192) bf16 = 25 MB

    sh_conv_kernel<<<BATCH * NT, 64, 0, stream>>>(src, patches, pdist, pidx, y_ws);
    prop_norm_kernel<<<(BATCH * NS) / 8, 192, 0, stream>>>(y_ws, prop_idx, prop_dist, out);
}

// Round 4
// 60.336 us; speedup vs baseline: 1.2404x; 1.2404x over previous
//
#include <hip/hip_runtime.h>
#include <math.h>

// Problem constants (fixed by setup_inputs)
#define BATCH   2
#define NS      8192
#define NT      2048
#define KNN     64
#define CH      64
#define SC      192           // NUM_SHELLS * CH
#define YROW    3072          // 16 * 192 bf16 elements per (b,n) point
#define FST     72            // featsT row stride (bf16 elems), 144 B, 16B-aligned
#define KST     72            // kern row stride

typedef __attribute__((ext_vector_type(8))) short short8;
typedef __attribute__((ext_vector_type(4))) float f32x4;

// round-to-nearest-even float -> bf16 bits
__device__ inline unsigned short f2bf(float x) {
    unsigned u = __float_as_uint(x);
    return (unsigned short)((u + 0x7fffu + ((u >> 16) & 1u)) >> 16);
}
__device__ inline float blo(unsigned v) { return __uint_as_float(v << 16); }
__device__ inline float bhi(unsigned v) { return __uint_as_float(v & 0xffff0000u); }

// ---------------------------------------------------------------------------
// Kernel 1 (MFMA): SH-Gaussian kernels + neighbor gather + contraction.
// One 256-thread block (4 waves) per (b,n) point.
//   Y^T[c][row48] computed as MFMA( A=featsT[c][k], B=kern[row48][k] ):
//   D[m=c][n=row48] = sum_k featsT[c][k]*kern[row48][k]
//                   = sum_k feats[k][c]*kern[row48][k]  = Y[row48][c].
// Wave w owns c-tile [16w,16w+16); 3 n-tiles x 2 k-steps = 6 MFMA/wave.
// ---------------------------------------------------------------------------
__global__ __launch_bounds__(256) void sh_conv_mfma(
    const float* __restrict__ src,      // (B,NS,CH)
    const float* __restrict__ patches,  // (B,NT,K,3)
    const float* __restrict__ pdist,    // (B,NT,K)
    const int*   __restrict__ pidx,     // (B,NT,K)
    unsigned short* __restrict__ y)     // (B,NT,16,192) bf16
{
    __shared__ unsigned short featsT[CH * FST];  // [c][k] 9216 B
    __shared__ unsigned short kern[48 * KST];    // [row48][k] 6912 B

    const int pt = blockIdx.x;           // b*NT + n
    const int b  = pt >> 11;             // NT = 2048
    const int t  = threadIdx.x;
    const int w  = t >> 6;               // wave 0..3
    const int l  = t & 63;               // lane

    // ---- Phase A1: gather + transpose into featsT[c=lane][k] ----
    {
        const int* idxp = pidx + pt * KNN;
        #pragma unroll
        for (int ko = 0; ko < 2; ++ko) {
            const int kbase = w * 16 + ko * 8;
            float v[8];
            #pragma unroll
            for (int j = 0; j < 8; ++j) {
                const int id = idxp[kbase + j];          // wave-uniform -> s_load
                v[j] = src[((size_t)(b * NS + id)) * CH + l];  // coalesced 256B row
            }
            uint4 pk;
            pk.x = (unsigned)f2bf(v[0]) | ((unsigned)f2bf(v[1]) << 16);
            pk.y = (unsigned)f2bf(v[2]) | ((unsigned)f2bf(v[3]) << 16);
            pk.z = (unsigned)f2bf(v[4]) | ((unsigned)f2bf(v[5]) << 16);
            pk.w = (unsigned)f2bf(v[6]) | ((unsigned)f2bf(v[7]) << 16);
            *(uint4*)&featsT[l * FST + kbase] = pk;      // ds_write_b128
        }
    }

    // ---- Phase A2: kern[row48 = ys*3+s][k] = bf16( sh[ys]*w[s]/64 ) ----
    {
        const int k  = t & 63;
        const int rg = t >> 6;           // ys block: ys = rg*4 .. rg*4+3
        const float* pv = patches + ((size_t)pt * KNN + k) * 3;
        const float px = pv[0], py = pv[1], pz = pv[2];
        const float d  = pdist[pt * KNN + k];
        const float inv = 1.0f / (d + 1e-8f);
        const float x = px * inv, yy = py * inv, z = pz * inv;
        const float x2 = x * x, y2 = yy * yy, z2 = z * z;

        float sh[16];
        sh[0]  = 0.28209479177387814f;
        sh[1]  = 0.4886025119029199f * yy;
        sh[2]  = 0.4886025119029199f * z;
        sh[3]  = 0.4886025119029199f * x;
        sh[4]  = 1.0925484305920792f * x * yy;
        sh[5]  = 1.0925484305920792f * yy * z;
        sh[6]  = 0.31539156525252005f * (3.0f * z2 - 1.0f);
        sh[7]  = 1.0925484305920792f * x * z;
        sh[8]  = 0.5462742152960396f * (x2 - y2);
        sh[9]  = 0.5900435899266435f * yy * (3.0f * x2 - y2);
        sh[10] = 2.890611442640554f  * x * yy * z;
        sh[11] = 0.4570457994644658f * yy * (5.0f * z2 - 1.0f);
        sh[12] = 0.3731763325901154f * z * (5.0f * z2 - 3.0f);
        sh[13] = 0.4570457994644658f * x * (5.0f * z2 - 1.0f);
        sh[14] = 1.445305721320277f  * z * (x2 - y2);
        sh[15] = 0.5900435899266435f * x * (x2 - 3.0f * y2);

        const float GS = 6.23832462504f;            // ln2 * 9
        float w0 = expf(-GS * d * d);
        const float dm1 = d - 0.5f;
        float w1 = expf(-GS * dm1 * dm1);
        const float dm2 = d - 1.0f;
        float w2 = expf(-GS * dm2 * dm2);
        const float wn = ((d <= 1.0f) ? 1.0f : 0.0f) * (1.0f / 64.0f)
                         / (w0 + w1 + w2 + 1e-8f);  // fold 1/K
        w0 *= wn; w1 *= wn; w2 *= wn;

        const int ys0 = rg * 4;
        #pragma unroll
        for (int i = 0; i < 4; ++i) {
            const float s = sh[ys0 + i];
            const int r0 = (ys0 + i) * 3;
            kern[(r0 + 0) * KST + k] = f2bf(s * w0);
            kern[(r0 + 1) * KST + k] = f2bf(s * w1);
            kern[(r0 + 2) * KST + k] = f2bf(s * w2);
        }
    }
    __syncthreads();

    // ---- Phase B: MFMA. lane: mhat = l&15, k-octet g = l>>4 ----
    const int mh = l & 15;
    const int g  = l >> 4;
    f32x4 acc0 = {0.f, 0.f, 0.f, 0.f};
    f32x4 acc1 = {0.f, 0.f, 0.f, 0.f};
    f32x4 acc2 = {0.f, 0.f, 0.f, 0.f};

    #pragma unroll
    for (int k0 = 0; k0 < 64; k0 += 32) {
        const int kofs = k0 + g * 8;
        const short8 af = *(const short8*)&featsT[(w * 16 + mh) * FST + kofs];
        const short8 b0 = *(const short8*)&kern[( 0 + mh) * KST + kofs];
        const short8 b1 = *(const short8*)&kern[(16 + mh) * KST + kofs];
        const short8 b2 = *(const short8*)&kern[(32 + mh) * KST + kofs];
        acc0 = __builtin_amdgcn_mfma_f32_16x16x32_bf16(af, b0, acc0, 0, 0, 0);
        acc1 = __builtin_amdgcn_mfma_f32_16x16x32_bf16(af, b1, acc1, 0, 0, 0);
        acc2 = __builtin_amdgcn_mfma_f32_16x16x32_bf16(af, b2, acc2, 0, 0, 0);
    }

    // ---- Store: lane reg r holds Y^T[c = w*16 + 4g + r][row48 = tn*16 + mh]
    unsigned short* yb = y + (size_t)pt * YROW;
    {
        const int cbase = w * 16 + g * 4;
        #pragma unroll
        for (int tn = 0; tn < 3; ++tn) {
            const f32x4 a = (tn == 0) ? acc0 : (tn == 1) ? acc1 : acc2;
            const int row48 = tn * 16 + mh;
            const int ys = row48 / 3, s = row48 % 3;
            uint2 o;
            o.x = (unsigned)f2bf(a[0]) | ((unsigned)f2bf(a[1]) << 16);
            o.y = (unsigned)f2bf(a[2]) | ((unsigned)f2bf(a[3]) << 16);
            *(uint2*)(yb + ys * SC + s * CH + cbase) = o;
        }
    }
}

// ---------------------------------------------------------------------------
// Kernel 2: UNCHANGED from round 3 (attribution control).
// ---------------------------------------------------------------------------
__global__ __launch_bounds__(192, 4) void prop_norm_kernel(
    const unsigned short* __restrict__ y, // (B,NT,16,192) bf16
    const int*   __restrict__ prop_idx,   // (B,NS,3)
    const float* __restrict__ prop_dist,  // (B,NS,3)
    float* __restrict__ out)              // (B,NS,768)
{
    const int t  = threadIdx.x;
    const int lp = t / 24;                // local point 0..7
    const int u  = t % 24;                // col-group: cols 8u..8u+7
    const int pt = blockIdx.x * 8 + lp;   // b*NS + ns
    const int b  = pt >> 13;              // NS = 8192

    const int   i0 = prop_idx[pt * 3 + 0];
    const int   i1 = prop_idx[pt * 3 + 1];
    const int   i2 = prop_idx[pt * 3 + 2];
    const float d0 = prop_dist[pt * 3 + 0];
    const float d1 = prop_dist[pt * 3 + 1];
    const float d2 = prop_dist[pt * 3 + 2];

    float w0 = 1.0f / (d0 * d0 + 1e-8f);
    float w1 = 1.0f / (d1 * d1 + 1e-8f);
    float w2 = 1.0f / (d2 * d2 + 1e-8f);
    const float wi = 1.0f / (w0 + w1 + w2);
    w0 *= wi; w1 *= wi; w2 *= wi;

    const uint4* p0 = (const uint4*)(y + ((size_t)(b * NT + i0)) * YROW) + u;
    const uint4* p1 = (const uint4*)(y + ((size_t)(b * NT + i1)) * YROW) + u;
    const uint4* p2 = (const uint4*)(y + ((size_t)(b * NT + i2)) * YROW) + u;

    float nsum[4][8];
    #pragma unroll
    for (int lq = 0; lq < 4; ++lq)
        #pragma unroll
        for (int j = 0; j < 8; ++j) nsum[lq][j] = 0.f;

    #pragma unroll
    for (int gq = 0; gq < 4; ++gq) {      // 4 batches of 4 ys
        uint4 A[4], Bv[4], Cv[4];
        #pragma unroll
        for (int j = 0; j < 4; ++j) {
            A[j]  = p0[(gq * 4 + j) * 24];
            Bv[j] = p1[(gq * 4 + j) * 24];
            Cv[j] = p2[(gq * 4 + j) * 24];
        }
        #pragma unroll
        for (int j = 0; j < 4; ++j) {
            const int ys = gq * 4 + j;
            const int lidx = (ys == 0) ? 0 : (ys < 4) ? 1 : (ys < 9) ? 2 : 3;
            const unsigned aw[4] = {A[j].x,  A[j].y,  A[j].z,  A[j].w};
            const unsigned bw[4] = {Bv[j].x, Bv[j].y, Bv[j].z, Bv[j].w};
            const unsigned cw[4] = {Cv[j].x, Cv[j].y, Cv[j].z, Cv[j].w};
            #pragma unroll
            for (int q = 0; q < 4; ++q) {
                const float vlo = w0 * blo(aw[q]) + w1 * blo(bw[q]) + w2 * blo(cw[q]);
                const float vhi = w0 * bhi(aw[q]) + w1 * bhi(bw[q]) + w2 * bhi(cw[q]);
                nsum[lidx][2 * q]     += vlo * vlo;
                nsum[lidx][2 * q + 1] += vhi * vhi;
            }
        }
    }

    float* ob = out + (size_t)pt * (4 * SC) + u * 8;
    #pragma unroll
    for (int lq = 0; lq < 4; ++lq) {
        float4 o0, o1;
        o0.x = sqrtf(fmaxf(nsum[lq][0], 1e-8f));
        o0.y = sqrtf(fmaxf(nsum[lq][1], 1e-8f));
        o0.z = sqrtf(fmaxf(nsum[lq][2], 1e-8f));
        o0.w = sqrtf(fmaxf(nsum[lq][3], 1e-8f));
        o1.x = sqrtf(fmaxf(nsum[lq][4], 1e-8f));
        o1.y = sqrtf(fmaxf(nsum[lq][5], 1e-8f));
        o1.z = sqrtf(fmaxf(nsum[lq][6], 1e-8f));
        o1.w = sqrtf(fmaxf(nsum[lq][7], 1e-8f));
        *(float4*)(ob + lq * SC)     = o0;
        *(float4*)(ob + lq * SC + 4) = o1;
    }
}

// ---------------------------------------------------------------------------
extern "C" void kernel_launch(void* const* d_in, const int* in_sizes, int n_in,
                              void* d_out, int out_size, void* d_ws, size_t ws_size,
                              hipStream_t stream) {
    const float* src       = (const float*)d_in[0];  // source_feats (B,NS,CH)
    const float* patches   = (const float*)d_in[1];  // (B,NT,K,3)
    const float* pdist     = (const float*)d_in[2];  // (B,NT,K)
    const int*   pidx      = (const int*)d_in[3];    // (B,NT,K)
    const int*   prop_idx  = (const int*)d_in[4];    // (B,NS,PP)
    const float* prop_dist = (const float*)d_in[5];  // (B,NS,PP)
    float*       out       = (float*)d_out;          // (B,NS,768)
    unsigned short* y_ws   = (unsigned short*)d_ws;  // (B,NT,16,192) bf16 = 25 MB

    sh_conv_mfma<<<BATCH * NT, 256, 0, stream>>>(src, patches, pdist, pidx, y_ws);
    prop_norm_kernel<<<(BATCH * NS) / 8, 192, 0, stream>>>(y_ws, prop_idx, prop_dist, out);
}

// Round 5
// 55.627 us; speedup vs baseline: 1.3454x; 1.0847x over previous
//
#include <hip/hip_runtime.h>
#include <math.h>

// Problem constants (fixed by setup_inputs)
#define BATCH   2
#define NS      8192
#define NT      2048
#define KNN     64
#define CH      64
#define SC      192           // NUM_SHELLS * CH
#define NPT     4096          // BATCH * NT
#define FST     72            // featsT row stride (bf16 elems)
#define KST     72            // kern row stride

typedef __attribute__((ext_vector_type(8))) short short8;
typedef __attribute__((ext_vector_type(4))) float f32x4;

// one-instruction packed f32->bf16 (RNE), lo -> bits[15:0], hi -> bits[31:16]
__device__ inline unsigned cvtpk(float lo, float hi) {
    unsigned r;
    asm("v_cvt_pk_bf16_f32 %0, %1, %2" : "=v"(r) : "v"(lo), "v"(hi));
    return r;
}
__device__ inline float blo(unsigned v) { return __uint_as_float(v << 16); }
__device__ inline float bhi(unsigned v) { return __uint_as_float(v & 0xffff0000u); }

// ---------------------------------------------------------------------------
// Kernel 1 (MFMA): SH-Gaussian kernels + neighbor gather + contraction.
// One 256-thread block (4 waves) per (b,n) point.
// y stored bf16 in SLAB-TRANSPOSED layout y[ys][pt][192] so that kernel 2's
// concurrent reads at a given ys hit a 1.5 MB slab (fits per-XCD L2).
// ---------------------------------------------------------------------------
__global__ __launch_bounds__(256) void sh_conv_mfma(
    const float* __restrict__ src,      // (B,NS,CH)
    const float* __restrict__ patches,  // (B,NT,K,3)
    const float* __restrict__ pdist,    // (B,NT,K)
    const int*   __restrict__ pidx,     // (B,NT,K)
    unsigned short* __restrict__ y)     // (16, NPT, 192) bf16
{
    __shared__ unsigned short featsT[CH * FST];  // [c][k] 9216 B
    __shared__ unsigned short kern[48 * KST];    // [row48][k] 6912 B

    const int pt = blockIdx.x;           // b*NT + n
    const int b  = pt >> 11;             // NT = 2048
    const int t  = threadIdx.x;
    const int w  = t >> 6;               // wave 0..3
    const int l  = t & 63;               // lane

    // ---- Phase A1: gather + transpose into featsT[c=lane][k] ----
    {
        const int* idxp = pidx + pt * KNN;
        #pragma unroll
        for (int ko = 0; ko < 2; ++ko) {
            const int kbase = w * 16 + ko * 8;
            float v[8];
            #pragma unroll
            for (int j = 0; j < 8; ++j) {
                const int id = idxp[kbase + j];          // wave-uniform -> s_load
                v[j] = src[((size_t)(b * NS + id)) * CH + l];  // coalesced 256B row
            }
            uint4 pk;
            pk.x = cvtpk(v[0], v[1]);
            pk.y = cvtpk(v[2], v[3]);
            pk.z = cvtpk(v[4], v[5]);
            pk.w = cvtpk(v[6], v[7]);
            *(uint4*)&featsT[l * FST + kbase] = pk;      // ds_write_b128
        }
    }

    // ---- Phase A2: kern[row48 = ys*3+s][k] = bf16( sh[ys]*w[s]/64 ) ----
    {
        const int k  = l;
        const float* pv = patches + ((size_t)pt * KNN + k) * 3;
        const float px = pv[0], py = pv[1], pz = pv[2];
        const float d  = pdist[pt * KNN + k];
        const float inv = 1.0f / (d + 1e-8f);
        const float x = px * inv, yy = py * inv, z = pz * inv;
        const float x2 = x * x, y2 = yy * yy, z2 = z * z;

        float sh[16];
        sh[0]  = 0.28209479177387814f;
        sh[1]  = 0.4886025119029199f * yy;
        sh[2]  = 0.4886025119029199f * z;
        sh[3]  = 0.4886025119029199f * x;
        sh[4]  = 1.0925484305920792f * x * yy;
        sh[5]  = 1.0925484305920792f * yy * z;
        sh[6]  = 0.31539156525252005f * (3.0f * z2 - 1.0f);
        sh[7]  = 1.0925484305920792f * x * z;
        sh[8]  = 0.5462742152960396f * (x2 - y2);
        sh[9]  = 0.5900435899266435f * yy * (3.0f * x2 - y2);
        sh[10] = 2.890611442640554f  * x * yy * z;
        sh[11] = 0.4570457994644658f * yy * (5.0f * z2 - 1.0f);
        sh[12] = 0.3731763325901154f * z * (5.0f * z2 - 3.0f);
        sh[13] = 0.4570457994644658f * x * (5.0f * z2 - 1.0f);
        sh[14] = 1.445305721320277f  * z * (x2 - y2);
        sh[15] = 0.5900435899266435f * x * (x2 - 3.0f * y2);

        // exp(-ln2*9*t^2) == exp2(-9*t^2): one v_exp_f32 each
        float w0 = exp2f(-9.0f * d * d);
        const float dm1 = d - 0.5f;
        float w1 = exp2f(-9.0f * dm1 * dm1);
        const float dm2 = d - 1.0f;
        float w2 = exp2f(-9.0f * dm2 * dm2);
        const float wn = ((d <= 1.0f) ? 1.0f : 0.0f) * (1.0f / 64.0f)
                         / (w0 + w1 + w2 + 1e-8f);  // fold 1/K
        w0 *= wn; w1 *= wn; w2 *= wn;

        const int ys0 = w * 4;           // this wave's ys quarter
        #pragma unroll
        for (int i = 0; i < 4; ++i) {
            const float s = sh[ys0 + i];
            const int r0 = (ys0 + i) * 3;
            const float p0 = s * w0, p1 = s * w1, p2 = s * w2;
            kern[(r0 + 0) * KST + k] = (unsigned short)cvtpk(p0, p0);
            kern[(r0 + 1) * KST + k] = (unsigned short)cvtpk(p1, p1);
            kern[(r0 + 2) * KST + k] = (unsigned short)cvtpk(p2, p2);
        }
    }
    __syncthreads();

    // ---- Phase B: MFMA. lane: mhat = l&15, k-octet g = l>>4 ----
    const int mh = l & 15;
    const int g  = l >> 4;
    f32x4 acc0 = {0.f, 0.f, 0.f, 0.f};
    f32x4 acc1 = {0.f, 0.f, 0.f, 0.f};
    f32x4 acc2 = {0.f, 0.f, 0.f, 0.f};

    #pragma unroll
    for (int k0 = 0; k0 < 64; k0 += 32) {
        const int kofs = k0 + g * 8;
        const short8 af = *(const short8*)&featsT[(w * 16 + mh) * FST + kofs];
        const short8 b0 = *(const short8*)&kern[( 0 + mh) * KST + kofs];
        const short8 b1 = *(const short8*)&kern[(16 + mh) * KST + kofs];
        const short8 b2 = *(const short8*)&kern[(32 + mh) * KST + kofs];
        acc0 = __builtin_amdgcn_mfma_f32_16x16x32_bf16(af, b0, acc0, 0, 0, 0);
        acc1 = __builtin_amdgcn_mfma_f32_16x16x32_bf16(af, b1, acc1, 0, 0, 0);
        acc2 = __builtin_amdgcn_mfma_f32_16x16x32_bf16(af, b2, acc2, 0, 0, 0);
    }

    // ---- Store: lane reg r = Y^T[c = w*16+4g+r][row48 = tn*16+mh] ----
    {
        const int cbase = w * 16 + g * 4;
        #pragma unroll
        for (int tn = 0; tn < 3; ++tn) {
            const f32x4 a = (tn == 0) ? acc0 : (tn == 1) ? acc1 : acc2;
            const int row48 = tn * 16 + mh;
            const int ys = row48 / 3, s = row48 - ys * 3;
            uint2 o;
            o.x = cvtpk(a[0], a[1]);
            o.y = cvtpk(a[2], a[3]);
            *(uint2*)(y + ((size_t)ys * NPT + pt) * SC + s * CH + cbase) = o;
        }
    }
}

// ---------------------------------------------------------------------------
// Kernel 2: inverse-square-distance propagation + per-degree norms.
// 192 threads = 8 points x 24 col-groups. All 2048 blocks co-resident
// (8 blocks/CU via launch_bounds); the unrolled ys sweep reads one 1.5 MB
// slab at a time -> per-XCD L2 resident. asm memory fence per ys stops the
// scheduler from hoisting the whole load window.
// ---------------------------------------------------------------------------
__global__ __launch_bounds__(192, 6) void prop_norm_kernel(
    const unsigned short* __restrict__ y, // (16, NPT, 192) bf16
    const int*   __restrict__ prop_idx,   // (B,NS,3)
    const float* __restrict__ prop_dist,  // (B,NS,3)
    float* __restrict__ out)              // (B,NS,768)
{
    const int t  = threadIdx.x;
    const int lp = t / 24;                // local point 0..7
    const int u  = t % 24;                // col-group: cols 8u..8u+7
    const int pt = blockIdx.x * 8 + lp;   // b*NS + ns
    const int b  = pt >> 13;              // NS = 8192

    const int   i0 = prop_idx[pt * 3 + 0];
    const int   i1 = prop_idx[pt * 3 + 1];
    const int   i2 = prop_idx[pt * 3 + 2];
    const float d0 = prop_dist[pt * 3 + 0];
    const float d1 = prop_dist[pt * 3 + 1];
    const float d2 = prop_dist[pt * 3 + 2];

    float w0 = 1.0f / (d0 * d0 + 1e-8f);
    float w1 = 1.0f / (d1 * d1 + 1e-8f);
    float w2 = 1.0f / (d2 * d2 + 1e-8f);
    const float wi = 1.0f / (w0 + w1 + w2);
    w0 *= wi; w1 *= wi; w2 *= wi;

    const int t0 = b * NT + i0;
    const int t1 = b * NT + i1;
    const int t2 = b * NT + i2;
    const uint4* yq = (const uint4*)y;    // 24 uint4 per (ys,pt) row

    float nsum[4][8];
    #pragma unroll
    for (int lq = 0; lq < 4; ++lq)
        #pragma unroll
        for (int j = 0; j < 8; ++j) nsum[lq][j] = 0.f;

    #pragma unroll
    for (int ys = 0; ys < 16; ++ys) {
        asm("" ::: "memory");             // keep load window ~1 ys slab
        const uint4 A  = yq[((size_t)ys * NPT + t0) * 24 + u];
        const uint4 Bv = yq[((size_t)ys * NPT + t1) * 24 + u];
        const uint4 Cv = yq[((size_t)ys * NPT + t2) * 24 + u];
        const int lidx = (ys == 0) ? 0 : (ys < 4) ? 1 : (ys < 9) ? 2 : 3;
        const unsigned aw[4] = {A.x,  A.y,  A.z,  A.w};
        const unsigned bw[4] = {Bv.x, Bv.y, Bv.z, Bv.w};
        const unsigned cw[4] = {Cv.x, Cv.y, Cv.z, Cv.w};
        #pragma unroll
        for (int q = 0; q < 4; ++q) {
            const float vlo = w0 * blo(aw[q]) + w1 * blo(bw[q]) + w2 * blo(cw[q]);
            const float vhi = w0 * bhi(aw[q]) + w1 * bhi(bw[q]) + w2 * bhi(cw[q]);
            nsum[lidx][2 * q]     += vlo * vlo;
            nsum[lidx][2 * q + 1] += vhi * vhi;
        }
    }

    float* ob = out + (size_t)pt * (4 * SC) + u * 8;
    #pragma unroll
    for (int lq = 0; lq < 4; ++lq) {
        float4 o0, o1;
        o0.x = sqrtf(fmaxf(nsum[lq][0], 1e-8f));
        o0.y = sqrtf(fmaxf(nsum[lq][1], 1e-8f));
        o0.z = sqrtf(fmaxf(nsum[lq][2], 1e-8f));
        o0.w = sqrtf(fmaxf(nsum[lq][3], 1e-8f));
        o1.x = sqrtf(fmaxf(nsum[lq][4], 1e-8f));
        o1.y = sqrtf(fmaxf(nsum[lq][5], 1e-8f));
        o1.z = sqrtf(fmaxf(nsum[lq][6], 1e-8f));
        o1.w = sqrtf(fmaxf(nsum[lq][7], 1e-8f));
        *(float4*)(ob + lq * SC)     = o0;
        *(float4*)(ob + lq * SC + 4) = o1;
    }
}

// ---------------------------------------------------------------------------
extern "C" void kernel_launch(void* const* d_in, const int* in_sizes, int n_in,
                              void* d_out, int out_size, void* d_ws, size_t ws_size,
                              hipStream_t stream) {
    const float* src       = (const float*)d_in[0];  // source_feats (B,NS,CH)
    const float* patches   = (const float*)d_in[1];  // (B,NT,K,3)
    const float* pdist     = (const float*)d_in[2];  // (B,NT,K)
    const int*   pidx      = (const int*)d_in[3];    // (B,NT,K)
    const int*   prop_idx  = (const int*)d_in[4];    // (B,NS,PP)
    const float* prop_dist = (const float*)d_in[5];  // (B,NS,PP)
    float*       out       = (float*)d_out;          // (B,NS,768)
    unsigned short* y_ws   = (unsigned short*)d_ws;  // (16, NPT, 192) bf16 = 25 MB

    sh_conv_mfma<<<BATCH * NT, 256, 0, stream>>>(src, patches, pdist, pidx, y_ws);
    prop_norm_kernel<<<(BATCH * NS) / 8, 192, 0, stream>>>(y_ws, prop_idx, prop_dist, out);
}

// Round 6
// 50.763 us; speedup vs baseline: 1.4743x; 1.0958x over previous
//
#include <hip/hip_runtime.h>
#include <math.h>

// Problem constants (fixed by setup_inputs)
#define BATCH   2
#define NS      8192
#define NT      2048
#define KNN     64
#define CH      64
#define SC      192           // NUM_SHELLS * CH
#define NPT     4096          // BATCH * NT
#define FST     72            // featsT row stride (bf16 elems)
#define KST     72            // kern row stride

typedef __attribute__((ext_vector_type(8))) short short8;
typedef __attribute__((ext_vector_type(4))) float f32x4;

// one-instruction packed f32->bf16 (RNE), lo -> bits[15:0], hi -> bits[31:16]
__device__ inline unsigned cvtpk(float lo, float hi) {
    unsigned r;
    asm("v_cvt_pk_bf16_f32 %0, %1, %2" : "=v"(r) : "v"(lo), "v"(hi));
    return r;
}
__device__ inline float blo(unsigned v) { return __uint_as_float(v << 16); }
__device__ inline float bhi(unsigned v) { return __uint_as_float(v & 0xffff0000u); }

// ---------------------------------------------------------------------------
// Kernel 1 (MFMA): UNCHANGED from round 5 (attribution control).
// y stored bf16, layout y[ys][pt][192]: each (ys,pt,s) 64-ch chunk = one
// 128 B cache line.
// ---------------------------------------------------------------------------
__global__ __launch_bounds__(256) void sh_conv_mfma(
    const float* __restrict__ src,      // (B,NS,CH)
    const float* __restrict__ patches,  // (B,NT,K,3)
    const float* __restrict__ pdist,    // (B,NT,K)
    const int*   __restrict__ pidx,     // (B,NT,K)
    unsigned short* __restrict__ y)     // (16, NPT, 192) bf16
{
    __shared__ unsigned short featsT[CH * FST];  // [c][k] 9216 B
    __shared__ unsigned short kern[48 * KST];    // [row48][k] 6912 B

    const int pt = blockIdx.x;           // b*NT + n
    const int b  = pt >> 11;             // NT = 2048
    const int t  = threadIdx.x;
    const int w  = t >> 6;               // wave 0..3
    const int l  = t & 63;               // lane

    // ---- Phase A1: gather + transpose into featsT[c=lane][k] ----
    {
        const int* idxp = pidx + pt * KNN;
        #pragma unroll
        for (int ko = 0; ko < 2; ++ko) {
            const int kbase = w * 16 + ko * 8;
            float v[8];
            #pragma unroll
            for (int j = 0; j < 8; ++j) {
                const int id = idxp[kbase + j];          // wave-uniform -> s_load
                v[j] = src[((size_t)(b * NS + id)) * CH + l];  // coalesced 256B row
            }
            uint4 pk;
            pk.x = cvtpk(v[0], v[1]);
            pk.y = cvtpk(v[2], v[3]);
            pk.z = cvtpk(v[4], v[5]);
            pk.w = cvtpk(v[6], v[7]);
            *(uint4*)&featsT[l * FST + kbase] = pk;      // ds_write_b128
        }
    }

    // ---- Phase A2: kern[row48 = ys*3+s][k] = bf16( sh[ys]*w[s]/64 ) ----
    {
        const int k  = l;
        const float* pv = patches + ((size_t)pt * KNN + k) * 3;
        const float px = pv[0], py = pv[1], pz = pv[2];
        const float d  = pdist[pt * KNN + k];
        const float inv = 1.0f / (d + 1e-8f);
        const float x = px * inv, yy = py * inv, z = pz * inv;
        const float x2 = x * x, y2 = yy * yy, z2 = z * z;

        float sh[16];
        sh[0]  = 0.28209479177387814f;
        sh[1]  = 0.4886025119029199f * yy;
        sh[2]  = 0.4886025119029199f * z;
        sh[3]  = 0.4886025119029199f * x;
        sh[4]  = 1.0925484305920792f * x * yy;
        sh[5]  = 1.0925484305920792f * yy * z;
        sh[6]  = 0.31539156525252005f * (3.0f * z2 - 1.0f);
        sh[7]  = 1.0925484305920792f * x * z;
        sh[8]  = 0.5462742152960396f * (x2 - y2);
        sh[9]  = 0.5900435899266435f * yy * (3.0f * x2 - y2);
        sh[10] = 2.890611442640554f  * x * yy * z;
        sh[11] = 0.4570457994644658f * yy * (5.0f * z2 - 1.0f);
        sh[12] = 0.3731763325901154f * z * (5.0f * z2 - 3.0f);
        sh[13] = 0.4570457994644658f * x * (5.0f * z2 - 1.0f);
        sh[14] = 1.445305721320277f  * z * (x2 - y2);
        sh[15] = 0.5900435899266435f * x * (x2 - 3.0f * y2);

        // exp(-ln2*9*t^2) == exp2(-9*t^2): one v_exp_f32 each
        float w0 = exp2f(-9.0f * d * d);
        const float dm1 = d - 0.5f;
        float w1 = exp2f(-9.0f * dm1 * dm1);
        const float dm2 = d - 1.0f;
        float w2 = exp2f(-9.0f * dm2 * dm2);
        const float wn = ((d <= 1.0f) ? 1.0f : 0.0f) * (1.0f / 64.0f)
                         / (w0 + w1 + w2 + 1e-8f);  // fold 1/K
        w0 *= wn; w1 *= wn; w2 *= wn;

        const int ys0 = w * 4;           // this wave's ys quarter
        #pragma unroll
        for (int i = 0; i < 4; ++i) {
            const float s = sh[ys0 + i];
            const int r0 = (ys0 + i) * 3;
            const float p0 = s * w0, p1 = s * w1, p2 = s * w2;
            kern[(r0 + 0) * KST + k] = (unsigned short)cvtpk(p0, p0);
            kern[(r0 + 1) * KST + k] = (unsigned short)cvtpk(p1, p1);
            kern[(r0 + 2) * KST + k] = (unsigned short)cvtpk(p2, p2);
        }
    }
    __syncthreads();

    // ---- Phase B: MFMA. lane: mhat = l&15, k-octet g = l>>4 ----
    const int mh = l & 15;
    const int g  = l >> 4;
    f32x4 acc0 = {0.f, 0.f, 0.f, 0.f};
    f32x4 acc1 = {0.f, 0.f, 0.f, 0.f};
    f32x4 acc2 = {0.f, 0.f, 0.f, 0.f};

    #pragma unroll
    for (int k0 = 0; k0 < 64; k0 += 32) {
        const int kofs = k0 + g * 8;
        const short8 af = *(const short8*)&featsT[(w * 16 + mh) * FST + kofs];
        const short8 b0 = *(const short8*)&kern[( 0 + mh) * KST + kofs];
        const short8 b1 = *(const short8*)&kern[(16 + mh) * KST + kofs];
        const short8 b2 = *(const short8*)&kern[(32 + mh) * KST + kofs];
        acc0 = __builtin_amdgcn_mfma_f32_16x16x32_bf16(af, b0, acc0, 0, 0, 0);
        acc1 = __builtin_amdgcn_mfma_f32_16x16x32_bf16(af, b1, acc1, 0, 0, 0);
        acc2 = __builtin_amdgcn_mfma_f32_16x16x32_bf16(af, b2, acc2, 0, 0, 0);
    }

    // ---- Store: lane reg r = Y^T[c = w*16+4g+r][row48 = tn*16+mh] ----
    {
        const int cbase = w * 16 + g * 4;
        #pragma unroll
        for (int tn = 0; tn < 3; ++tn) {
            const f32x4 a = (tn == 0) ? acc0 : (tn == 1) ? acc1 : acc2;
            const int row48 = tn * 16 + mh;
            const int ys = row48 / 3, s = row48 - ys * 3;
            uint2 o;
            o.x = cvtpk(a[0], a[1]);
            o.y = cvtpk(a[2], a[3]);
            *(uint2*)(y + ((size_t)ys * NPT + pt) * SC + s * CH + cbase) = o;
        }
    }
}

// ---------------------------------------------------------------------------
// Kernel 2 (sliced): norms are column-separable, so partition work by
// (degree l, shell s) — each (ys,pt,s) chunk is one 128B line. Slot
// (= blockIdx&7, the round-robin XCD heuristic) owns a disjoint (l,s)
// subset, so each XCD's L2 fills only its ~3.5 MB slice of y once and
// serves all 12.6x reuse from L2. Nontemporal out stores avoid evicting
// the slice.
//   slot 0..2: (3,s)  [7 ys]     slot 3..5: (2,s)  [5 ys]
//   slot 6: (1,0)+(1,1) [6]      slot 7: (1,2)+(0,0)+(0,1)+(0,2) [6]
// Block: 256 thr = 32 points x 8 ch-groups (uint4 = 8 channels each).
// ---------------------------------------------------------------------------
template<int L, int S>
__device__ inline void proc_group(const unsigned short* __restrict__ y,
                                  int t0, int t1, int t2,
                                  float w0, float w1, float w2,
                                  int cg, float* __restrict__ ob)
{
    float ns[8];
    #pragma unroll
    for (int j = 0; j < 8; ++j) ns[j] = 0.f;

    #pragma unroll
    for (int m = 0; m <= 2 * L; ++m) {
        const int ys = L * L + m;
        const size_t base = (size_t)ys * NPT * SC + S * CH + cg * 8;
        const uint4 A  = *(const uint4*)(y + base + (size_t)t0 * SC);
        const uint4 Bv = *(const uint4*)(y + base + (size_t)t1 * SC);
        const uint4 Cv = *(const uint4*)(y + base + (size_t)t2 * SC);
        const unsigned aw[4] = {A.x,  A.y,  A.z,  A.w};
        const unsigned bw[4] = {Bv.x, Bv.y, Bv.z, Bv.w};
        const unsigned cw[4] = {Cv.x, Cv.y, Cv.z, Cv.w};
        #pragma unroll
        for (int q = 0; q < 4; ++q) {
            const float vlo = w0 * blo(aw[q]) + w1 * blo(bw[q]) + w2 * blo(cw[q]);
            const float vhi = w0 * bhi(aw[q]) + w1 * bhi(bw[q]) + w2 * bhi(cw[q]);
            ns[2 * q]     += vlo * vlo;
            ns[2 * q + 1] += vhi * vhi;
        }
    }

    f32x4 o0, o1;
    o0[0] = sqrtf(fmaxf(ns[0], 1e-8f));
    o0[1] = sqrtf(fmaxf(ns[1], 1e-8f));
    o0[2] = sqrtf(fmaxf(ns[2], 1e-8f));
    o0[3] = sqrtf(fmaxf(ns[3], 1e-8f));
    o1[0] = sqrtf(fmaxf(ns[4], 1e-8f));
    o1[1] = sqrtf(fmaxf(ns[5], 1e-8f));
    o1[2] = sqrtf(fmaxf(ns[6], 1e-8f));
    o1[3] = sqrtf(fmaxf(ns[7], 1e-8f));
    float* p = ob + L * SC + S * CH + cg * 8;
    __builtin_nontemporal_store(o0, (f32x4*)p);
    __builtin_nontemporal_store(o1, (f32x4*)(p + 4));
}

__global__ __launch_bounds__(256) void prop_norm_sliced(
    const unsigned short* __restrict__ y, // (16, NPT, 192) bf16
    const int*   __restrict__ prop_idx,   // (B,NS,3)
    const float* __restrict__ prop_dist,  // (B,NS,3)
    float* __restrict__ out)              // (B,NS,768)
{
    const int slot = blockIdx.x & 7;      // XCD pin (round-robin heuristic)
    const int bi   = blockIdx.x >> 3;
    const int t    = threadIdx.x;
    const int lp   = t >> 3;              // local point 0..31
    const int cg   = t & 7;               // channel group (8 ch, uint4)
    const int pt   = bi * 32 + lp;        // b*NS + ns
    const int b    = pt >> 13;            // NS = 8192

    const int   i0 = prop_idx[pt * 3 + 0];
    const int   i1 = prop_idx[pt * 3 + 1];
    const int   i2 = prop_idx[pt * 3 + 2];
    const float d0 = prop_dist[pt * 3 + 0];
    const float d1 = prop_dist[pt * 3 + 1];
    const float d2 = prop_dist[pt * 3 + 2];

    float w0 = 1.0f / (d0 * d0 + 1e-8f);
    float w1 = 1.0f / (d1 * d1 + 1e-8f);
    float w2 = 1.0f / (d2 * d2 + 1e-8f);
    const float wi = 1.0f / (w0 + w1 + w2);
    w0 *= wi; w1 *= wi; w2 *= wi;

    const int t0 = b * NT + i0;
    const int t1 = b * NT + i1;
    const int t2 = b * NT + i2;
    float* ob = out + (size_t)pt * (4 * SC);

    switch (slot) {
    case 0: proc_group<3, 0>(y, t0, t1, t2, w0, w1, w2, cg, ob); break;
    case 1: proc_group<3, 1>(y, t0, t1, t2, w0, w1, w2, cg, ob); break;
    case 2: proc_group<3, 2>(y, t0, t1, t2, w0, w1, w2, cg, ob); break;
    case 3: proc_group<2, 0>(y, t0, t1, t2, w0, w1, w2, cg, ob); break;
    case 4: proc_group<2, 1>(y, t0, t1, t2, w0, w1, w2, cg, ob); break;
    case 5: proc_group<2, 2>(y, t0, t1, t2, w0, w1, w2, cg, ob); break;
    case 6: proc_group<1, 0>(y, t0, t1, t2, w0, w1, w2, cg, ob);
            proc_group<1, 1>(y, t0, t1, t2, w0, w1, w2, cg, ob); break;
    default:proc_group<1, 2>(y, t0, t1, t2, w0, w1, w2, cg, ob);
            proc_group<0, 0>(y, t0, t1, t2, w0, w1, w2, cg, ob);
            proc_group<0, 1>(y, t0, t1, t2, w0, w1, w2, cg, ob);
            proc_group<0, 2>(y, t0, t1, t2, w0, w1, w2, cg, ob); break;
    }
}

// ---------------------------------------------------------------------------
extern "C" void kernel_launch(void* const* d_in, const int* in_sizes, int n_in,
                              void* d_out, int out_size, void* d_ws, size_t ws_size,
                              hipStream_t stream) {
    const float* src       = (const float*)d_in[0];  // source_feats (B,NS,CH)
    const float* patches   = (const float*)d_in[1];  // (B,NT,K,3)
    const float* pdist     = (const float*)d_in[2];  // (B,NT,K)
    const int*   pidx      = (const int*)d_in[3];    // (B,NT,K)
    const int*   prop_idx  = (const int*)d_in[4];    // (B,NS,PP)
    const float* prop_dist = (const float*)d_in[5];  // (B,NS,PP)
    float*       out       = (float*)d_out;          // (B,NS,768)
    unsigned short* y_ws   = (unsigned short*)d_ws;  // (16, NPT, 192) bf16 = 25 MB

    sh_conv_mfma<<<BATCH * NT, 256, 0, stream>>>(src, patches, pdist, pidx, y_ws);
    // 8 slots x 512 point-blocks (32 points/block)
    prop_norm_sliced<<<8 * (BATCH * NS / 32), 256, 0, stream>>>(y_ws, prop_idx, prop_dist, out);
}